// Round 7
// baseline (242.099 us; speedup 1.0000x reference)
//
#include <hip/hip_runtime.h>
#include <hip/hip_bf16.h>
#include <cstdint>
#include <cstddef>

// ---- problem constants ----
#define NIN   2048
#define RANK  64
#define R2    128      // 2*RANK
#define NROWS 16384    // 8*2048 flattened batch*seq rows

typedef __bf16 bf16x8 __attribute__((ext_vector_type(8)));
typedef float  f32x4  __attribute__((ext_vector_type(4)));
typedef unsigned short u16x8 __attribute__((ext_vector_type(8)));

__device__ __forceinline__ unsigned short f2bf(float f) {
  union { float f; unsigned u; } x; x.f = f;
  return (unsigned short)((x.u + 0x7fffu + ((x.u >> 16) & 1u)) >> 16);
}

// ---- 0) zero G + barrier counters (must be reset every call: graph replays) ----
__global__ void k_zero(float* __restrict__ G, int* __restrict__ cnt) {
  G[blockIdx.x * 256 + threadIdx.x] = 0.f;
  if (blockIdx.x == 0 && threadIdx.x < 8) cnt[threadIdx.x] = 0;
}

// ---- 1) k_prep: Mf (frag-order) fill + S-part of G via K-split atomics ----
// Mf chunk CI = (t*64 + J)*64 + lane holds M[t*16 + (lane&15)][J*32 + (lane>>4)*8 + e]
__global__ void k_prep(const float* __restrict__ U, const float* __restrict__ V,
                       unsigned short* __restrict__ Mf, float* __restrict__ G) {
  int b = blockIdx.x, tid = threadIdx.x;
  if (b < 128) {
    int CI = b * 256 + tid;
    int lane = CI & 63, J = (CI >> 6) & 63, t = CI >> 12;
    int n = t * 16 + (lane & 15);
    int k0 = J * 32 + (lane >> 4) * 8;
    const float* src = (n < RANK) ? (U + n) : (V + (n - RANK));
    u16x8 h;
#pragma unroll
    for (int e = 0; e < 8; ++e) h[e] = f2bf(src[(size_t)(k0 + e) * RANK]);
    *(u16x8*)(Mf + (size_t)CI * 8) = h;
  }
  int tile = b >> 3, ks = b & 7;
  int bi = tile >> 3, bj = tile & 7;
  int ty = tid >> 4, tx = tid & 15;
  int i = bi * 16 + ty, j = bj * 16 + tx;
  const float* Ai = (i < RANK) ? (U + i) : (V + (i - RANK));
  const float* Aj = (j < RANK) ? (U + j) : (V + (j - RANK));
  int k0 = ks * 256;
  float acc = 0.f;
#pragma unroll 8
  for (int k = k0; k < k0 + 256; ++k) acc += Ai[(size_t)k * RANK] * Aj[(size_t)k * RANK];
  if (i < RANK) atomicAdd(&G[(i + RANK) * R2 + j], -acc);
  else          atomicAdd(&G[(i - RANK) * R2 + j],  acc);
}

// ---- small GEMM tile helper: 16x16 tile t of (A + a*I)(B + b*I) ----
__device__ __forceinline__ void smallGemm(const float* __restrict__ A,
                                          const float* __restrict__ B,
                                          float* __restrict__ O,
                                          float a, float b, int t, int tid) {
  int i = (t >> 3) * 16 + (tid >> 4);
  int j = (t & 7) * 16 + (tid & 15);
  float acc = 0.f;
#pragma unroll 8
  for (int k = 0; k < R2; ++k) {
    float av = A[i * R2 + k]; if (k == i) av += a;
    float bv = B[k * R2 + j]; if (k == j) bv += b;
    acc += av * bv;
  }
  O[i * R2 + j] = acc;
}

// ---- inter-block barrier (all blocks of THIS grid are co-resident: grid=192<=256 CUs) ----
__device__ __forceinline__ void gbar(int* c, int target, int tid) {
  __syncthreads();
  if (tid == 0) {
    __threadfence();
    __hip_atomic_fetch_add(c, 1, __ATOMIC_RELEASE, __HIP_MEMORY_SCOPE_AGENT);
  }
  while (__hip_atomic_load(c, __ATOMIC_ACQUIRE, __HIP_MEMORY_SCOPE_AGENT) < target)
    __builtin_amdgcn_s_sleep(8);
}

// ---- 2) k_chainD: 4 polynomial stages + D, one launch, 192 blocks x 256 ----
__global__ __launch_bounds__(256) void k_chainD(const float* __restrict__ U,
                                                const float* __restrict__ V,
                                                float* __restrict__ mats,
                                                unsigned short* __restrict__ Df,
                                                int* __restrict__ cnt) {
  __shared__ float elds[16384];
  float* G_   = mats;
  float* G2_  = mats + 1 * 16384;
  float* G3_  = mats + 2 * 16384;
  float* G4_  = mats + 3 * 16384;
  float* G7_  = mats + 4 * 16384;
  float* G8_  = mats + 5 * 16384;
  float* H12_ = mats + 6 * 16384;
  float* H124_= mats + 7 * 16384;
  float* H_   = mats + 8 * 16384;
  float* G15_ = mats + 9 * 16384;
  const int cb = blockIdx.x, tid = threadIdx.x;

  if (cb < 64) smallGemm(G_, G_, G2_, 0.f, 0.f, cb, tid);
  gbar(&cnt[0], 192, tid);
  { int op = cb >> 6, t = cb & 63;
    if (op == 0)      smallGemm(G2_, G2_, G4_,  0.f, 0.f, t, tid);
    else if (op == 1) smallGemm(G2_, G_,  G3_,  0.f, 0.f, t, tid);
    else              smallGemm(G_,  G2_, H12_, 1.f, 1.f, t, tid); }
  gbar(&cnt[1], 192, tid);
  { int op = cb >> 6, t = cb & 63;
    if (op == 0)      smallGemm(G4_,  G4_, G8_,   0.f, 0.f, t, tid);
    else if (op == 1) smallGemm(G3_,  G4_, G7_,   0.f, 0.f, t, tid);
    else              smallGemm(H12_, G4_, H124_, 0.f, 1.f, t, tid); }
  gbar(&cnt[2], 192, tid);
  if (cb < 128) {
    int op = cb >> 6, t = cb & 63;
    if (op == 0) smallGemm(G7_,   G8_, G15_, 0.f, 0.f, t, tid);
    else         smallGemm(H124_, G8_, H_,   0.f, 1.f, t, tid);
  }
  gbar(&cnt[3], 192, tid);

  // ---- D = M * (2H - G15) * J, frag-order bf16; blocks 0..127, 16 rows each ----
  if (cb < 128) {
    const float4* H4 = (const float4*)H_;
    const float4* X4 = (const float4*)G15_;
#pragma unroll
    for (int it = 0; it < 16; ++it) {
      int i4 = it * 256 + tid;
      float4 h = H4[i4], x = X4[i4];
      float4 e = { 2.f*h.x - x.x, 2.f*h.y - x.y, 2.f*h.z - x.z, 2.f*h.w - x.w };
      ((float4*)elds)[i4] = e;
    }
    __syncthreads();
    int j = tid & 127, half = tid >> 7;
    int jj = (j < RANK) ? (j + RANK) : (j - RANK);
    float sgn = (j < RANK) ? -1.f : 1.f;
    int i0 = cb * 16 + half * 8;
    float acc[8] = {};
#pragma unroll 4
    for (int k = 0; k < RANK; ++k) {
      float e = sgn * elds[k * R2 + jj];
#pragma unroll
      for (int rr = 0; rr < 8; ++rr) acc[rr] += U[(i0 + rr) * RANK + k] * e;
    }
#pragma unroll 4
    for (int k = 0; k < RANK; ++k) {
      float e = sgn * elds[(k + RANK) * R2 + jj];
#pragma unroll
      for (int rr = 0; rr < 8; ++rr) acc[rr] += V[(i0 + rr) * RANK + k] * e;
    }
#pragma unroll
    for (int rr = 0; rr < 8; ++rr) {
      int i = i0 + rr;
      int t_ = i >> 4, lr = i & 15, J = j >> 5, lg = (j >> 3) & 3, e8 = j & 7;
      size_t CI = (size_t)(t_ * 4 + J) * 64 + lg * 16 + lr;
      Df[CI * 8 + e8] = f2bf(acc[rr]);
    }
  }
}

// ---- 3) k_main: fused T1 = input@M (LDS) then out = input + T1 @ D^T ----
// 512 blocks x 256 threads; block = 32-row stripe x all 2048 cols.
// LDS 73728B: abuf[w] (0..32KB) / rbuf f32 pad-36 (whole) / obuf[w] [32][68] (0..34816) / t1s @65536
__global__ __launch_bounds__(256) void k_main(const float* __restrict__ input,
                                              const unsigned short* __restrict__ Mf,
                                              const unsigned short* __restrict__ Df,
                                              float* __restrict__ out) {
  __shared__ __align__(16) unsigned char lds[73728];
  const int tid = threadIdx.x, lane = tid & 63, w = tid >> 6;
  const int lr = lane & 15, lg = lane >> 4;
  const int row0 = blockIdx.x * 32;
  unsigned char* abuf = lds + w * 8192;
  float* rbuf = (float*)lds;

  // ---- phase 1: wave w computes T1 partial over K in [w*512,(w+1)*512) ----
  f32x4 acc[2][8] = {};
  const float* gbase = input + (size_t)row0 * NIN + w * 512;
  const int Jbase = w * 16;
  float4 s0[8], s1[8];
  bf16x8 bx[8], by[8];

#define T1_SLOAD(KT)                                                          \
  _Pragma("unroll") for (int p = 0; p < 8; ++p) {                             \
    int id = p * 64 + lane; int r = id >> 4, C = id & 15;                     \
    const float* g = gbase + (size_t)r * NIN + (KT) * 128 + C * 8;            \
    s0[p] = *(const float4*)g; s1[p] = *(const float4*)(g + 4);               \
  }
#define T1_SWRITE()                                                           \
  _Pragma("unroll") for (int p = 0; p < 8; ++p) {                             \
    int id = p * 64 + lane; int r = id >> 4, C = id & 15;                     \
    u16x8 h;                                                                  \
    h[0] = f2bf(s0[p].x); h[1] = f2bf(s0[p].y);                               \
    h[2] = f2bf(s0[p].z); h[3] = f2bf(s0[p].w);                               \
    h[4] = f2bf(s1[p].x); h[5] = f2bf(s1[p].y);                               \
    h[6] = f2bf(s1[p].z); h[7] = f2bf(s1[p].w);                               \
    *(u16x8*)(abuf + r * 256 + ((C ^ (r & 7)) << 4)) = h;                     \
  }
#define T1_BLOAD(P, S)                                                        \
  _Pragma("unroll") for (int t = 0; t < 8; ++t)                               \
    P[t] = *(const bf16x8*)(Mf + ((size_t)(t * 64 + Jbase + (S)) * 64 + lane) * 8);

  T1_SLOAD(0);
  T1_SWRITE();
  T1_BLOAD(bx, 0);
#pragma unroll
  for (int s = 0; s < 16; ++s) {
    const int kt = s >> 2, j = s & 3;
    if (j == 0 && kt < 3) { T1_SLOAD(kt + 1); }
    bf16x8 a0, a1;
    {
      int C = j * 4 + lg;
      a0 = *(const bf16x8*)(abuf + lr * 256 + ((C ^ (lr & 7)) << 4));
      a1 = *(const bf16x8*)(abuf + (16 + lr) * 256 + ((C ^ ((16 + lr) & 7)) << 4));
    }
    if (s < 15) { if (s & 1) { T1_BLOAD(bx, s + 1); } else { T1_BLOAD(by, s + 1); } }
#pragma unroll
    for (int t = 0; t < 8; ++t) {
      bf16x8 bcur = (s & 1) ? by[t] : bx[t];
      acc[0][t] = __builtin_amdgcn_mfma_f32_16x16x32_bf16(a0, bcur, acc[0][t], 0, 0, 0);
      acc[1][t] = __builtin_amdgcn_mfma_f32_16x16x32_bf16(a1, bcur, acc[1][t], 0, 0, 0);
    }
    if (j == 3 && kt < 3) { T1_SWRITE(); }
  }

  __syncthreads();                      // (1) abuf done; rbuf overlays
#pragma unroll
  for (int m = 0; m < 2; ++m)
#pragma unroll
    for (int t = 0; t < 8; ++t) {
      int col = t * 16 + lr, row = m * 16 + lg * 4;
      *(f32x4*)&rbuf[((size_t)w * 128 + col) * 36 + row] = acc[m][t];
    }
  __syncthreads();                      // (2)
  // reduce into regs
  {
    int r = tid & 31, cg = tid >> 5;
    float sums[16];
#pragma unroll
    for (int i = 0; i < 16; ++i) {
      int col = cg * 16 + i;
      sums[i] = rbuf[(size_t)col * 36 + r]
              + rbuf[((size_t)128 + col) * 36 + r]
              + rbuf[((size_t)256 + col) * 36 + r]
              + rbuf[((size_t)384 + col) * 36 + r];
    }
    __syncthreads();                    // (3) rbuf reads done; t1s/obuf overlay OK
    u16x8 o1, o2;
#pragma unroll
    for (int i = 0; i < 8; ++i) { o1[i] = f2bf(sums[i]); o2[i] = f2bf(sums[8 + i]); }
    *(u16x8*)(lds + 65536 + r * 256 + (((cg * 2)     ^ (r & 7)) << 4)) = o1;
    *(u16x8*)(lds + 65536 + r * 256 + (((cg * 2 + 1) ^ (r & 7)) << 4)) = o2;
  }
  __syncthreads();                      // (4) t1s visible

  // ---- phase 2: out[row0..+32][:] = input + T1 @ D^T ----
  bf16x8 bq[2][4];
#pragma unroll
  for (int R = 0; R < 2; ++R)
#pragma unroll
    for (int J = 0; J < 4; ++J) {
      int row = R * 16 + lr, cc = J * 4 + lg;
      bq[R][J] = *(const bf16x8*)(lds + 65536 + row * 256 + ((cc ^ (row & 7)) << 4));
    }
  float* obufw = (float*)(lds + w * 8704);   // [32][68]
  bf16x8 xd[4], yd[4];
#define O_DLOAD(P, TTI)                                                       \
  _Pragma("unroll") for (int J = 0; J < 4; ++J)                               \
    P[J] = *(const bf16x8*)(Df + ((size_t)((w * 32 + (TTI)) * 4 + J) * 64 + lane) * 8);

  O_DLOAD(xd, 0);
#pragma unroll
  for (int g = 0; g < 8; ++g) {
#pragma unroll
    for (int tt = 0; tt < 4; ++tt) {
      const int tti = g * 4 + tt;
      if (tti < 31) { if (tti & 1) { O_DLOAD(xd, tti + 1); } else { O_DLOAD(yd, tti + 1); } }
#pragma unroll
      for (int R = 0; R < 2; ++R) {
        f32x4 o = {};
#pragma unroll
        for (int J = 0; J < 4; ++J) {
          bf16x8 d = (tti & 1) ? yd[J] : xd[J];
          o = __builtin_amdgcn_mfma_f32_16x16x32_bf16(d, bq[R][J], o, 0, 0, 0);
        }
        *(f32x4*)&obufw[(R * 16 + lr) * 68 + tt * 16 + lg * 4] = o;
      }
    }
#pragma unroll
    for (int c = 0; c < 8; ++c) {
      int id = c * 64 + lane, r = id >> 4, cc = id & 15;
      f32x4 v = *(const f32x4*)&obufw[r * 68 + cc * 4];
      int grow = row0 + r, gcol = w * 512 + g * 64 + cc * 4;
      float4 inv = *(const float4*)(input + (size_t)grow * NIN + gcol);
      float4 res = { v[0] + inv.x, v[1] + inv.y, v[2] + inv.z, v[3] + inv.w };
      *(float4*)(out + (size_t)grow * NIN + gcol) = res;
    }
  }
}

extern "C" void kernel_launch(void* const* d_in, const int* in_sizes, int n_in,
                              void* d_out, int out_size, void* d_ws, size_t ws_size,
                              hipStream_t stream) {
  const float* input = (const float*)d_in[0];
  const float* U     = (const float*)d_in[1];
  const float* V     = (const float*)d_in[2];
  float* out = (float*)d_out;
  char* ws = (char*)d_ws;

  float* mats = (float*)ws;                                               // 10 x 64KB
  float* G = mats;
  unsigned short* Mf = (unsigned short*)(ws + 10 * 65536);                // 512 KB
  unsigned short* Df = (unsigned short*)(ws + 10 * 65536 + 524288);       // 512 KB
  int* cnt = (int*)(ws + 10 * 65536 + 2 * 524288);                        // 8 ints

  k_zero<<<64, 256, 0, stream>>>(G, cnt);
  k_prep<<<512, 256, 0, stream>>>(U, V, Mf, G);
  k_chainD<<<192, 256, 0, stream>>>(U, V, mats, Df, cnt);
  k_main<<<512, 256, 0, stream>>>(input, Mf, Df, out);
}

// Round 8
// 195.653 us; speedup vs baseline: 1.2374x; 1.2374x over previous
//
#include <hip/hip_runtime.h>
#include <hip/hip_bf16.h>
#include <cstdint>
#include <cstddef>

// ---- problem constants ----
#define NIN   2048
#define RANK  64
#define R2    128      // 2*RANK
#define NROWS 16384    // 8*2048 flattened batch*seq rows

typedef __bf16 bf16x8 __attribute__((ext_vector_type(8)));
typedef float  f32x4  __attribute__((ext_vector_type(4)));
typedef unsigned short u16x8 __attribute__((ext_vector_type(8)));

__device__ __forceinline__ unsigned short f2bf(float f) {
  union { float f; unsigned u; } x; x.f = f;
  return (unsigned short)((x.u + 0x7fffu + ((x.u >> 16) & 1u)) >> 16);
}

// ---- 1) k_prep: Mf (frag-order) fill + G = J*(M^T M), no atomics ----
// blocks 0..127: Mf; blocks 128..191: G tiles over full K (no zero/atomic needed).
// Mf chunk CI = (t*64 + J)*64 + lane holds M[t*16 + (lane&15)][J*32 + (lane>>4)*8 + e]
__global__ void k_prep(const float* __restrict__ U, const float* __restrict__ V,
                       unsigned short* __restrict__ Mf, float* __restrict__ G) {
  int b = blockIdx.x, tid = threadIdx.x;
  if (b < 128) {
    int CI = b * 256 + tid;
    int lane = CI & 63, J = (CI >> 6) & 63, t = CI >> 12;
    int n = t * 16 + (lane & 15);
    int k0 = J * 32 + (lane >> 4) * 8;
    const float* src = (n < RANK) ? (U + n) : (V + (n - RANK));
    u16x8 h;
#pragma unroll
    for (int e = 0; e < 8; ++e) h[e] = f2bf(src[(size_t)(k0 + e) * RANK]);
    *(u16x8*)(Mf + (size_t)CI * 8) = h;
  } else {
    int tile = b - 128;                 // 0..63
    int bi = tile >> 3, bj = tile & 7;
    int ty = tid >> 4, tx = tid & 15;
    int i = bi * 16 + ty, j = bj * 16 + tx;
    const float* Ai = (i < RANK) ? (U + i) : (V + (i - RANK));
    const float* Aj = (j < RANK) ? (U + j) : (V + (j - RANK));
    float acc = 0.f;
#pragma unroll 8
    for (int k = 0; k < NIN; ++k) acc += Ai[(size_t)k * RANK] * Aj[(size_t)k * RANK];
    if (i < RANK) G[(i + RANK) * R2 + j] = -acc;
    else          G[(i - RANK) * R2 + j] =  acc;
  }
}

// ---- 2) generic small 128x128 GEMM: O = (A + a*I)(B + b*I), fp32 ----
struct SOp { const float* A; const float* B; float* O; float a, b; };
struct SOps { SOp op[3]; };
__global__ void k_small(SOps ops) {
  SOp o = ops.op[blockIdx.x >> 6];     // 64 blocks per op
  int t = blockIdx.x & 63;
  int i = (t >> 3) * 16 + (threadIdx.x >> 4);
  int j = (t & 7) * 16 + (threadIdx.x & 15);
  float acc = 0.f;
#pragma unroll 8
  for (int k = 0; k < R2; ++k) {
    float av = o.A[i * R2 + k]; if (k == i) av += o.a;
    float bv = o.B[k * R2 + j]; if (k == j) bv += o.b;
    acc += av * bv;
  }
  o.O[i * R2 + j] = acc;
}

// ---- 3) Df = bf16( M * ((2H - G15) * J) ) in FRAG-ORDER ----
// Df chunk CI = (t*4 + J)*64 + lane holds D[t*16 + (lane&15)][J*32 + (lane>>4)*8 + e]
__global__ void k_D(const float* __restrict__ U, const float* __restrict__ V,
                    const float* __restrict__ H, const float* __restrict__ G15,
                    unsigned short* __restrict__ Df) {
  int idx = blockIdx.x * 256 + threadIdx.x;  // i*128 + j, i < 2048
  int i = idx >> 7, j = idx & 127;
  int jj = (j < RANK) ? (j + RANK) : (j - RANK);
  float sgn = (j < RANK) ? -1.f : 1.f;
  float acc = 0.f;
#pragma unroll 8
  for (int k = 0; k < R2; ++k) {
    float m = (k < RANK) ? U[(size_t)i * RANK + k] : V[(size_t)i * RANK + (k - RANK)];
    float t = 2.f * H[k * R2 + jj] - G15[k * R2 + jj];
    acc += m * (sgn * t);
  }
  int t_ = i >> 4, lr = i & 15;
  int J = j >> 5, lg = (j >> 3) & 3, e = j & 7;
  size_t CI = (size_t)(t_ * 4 + J) * 64 + lg * 16 + lr;
  Df[CI * 8 + e] = f2bf(acc);
}

// ---- 4) k_main: fused T1 = input@M (LDS) then out = input + T1 @ D^T ----
// 512 blocks x 256 threads; block = 32-row stripe x all 2048 cols.
// LDS 73728B: abuf[w] (0..32KB) / rbuf f32 pad-36 (whole) / obuf[w] [32][68] (0..34816) / t1s @65536
__global__ __launch_bounds__(256) void k_main(const float* __restrict__ input,
                                              const unsigned short* __restrict__ Mf,
                                              const unsigned short* __restrict__ Df,
                                              float* __restrict__ out) {
  __shared__ __align__(16) unsigned char lds[73728];
  const int tid = threadIdx.x, lane = tid & 63, w = tid >> 6;
  const int lr = lane & 15, lg = lane >> 4;
  const int row0 = blockIdx.x * 32;
  unsigned char* abuf = lds + w * 8192;
  float* rbuf = (float*)lds;

  // ---- phase 1: wave w computes T1 partial over K in [w*512,(w+1)*512) ----
  f32x4 acc[2][8] = {};
  const float* gbase = input + (size_t)row0 * NIN + w * 512;
  const int Jbase = w * 16;
  float4 s0[8], s1[8];
  bf16x8 bx[8], by[8];

#define T1_SLOAD(KT)                                                          \
  _Pragma("unroll") for (int p = 0; p < 8; ++p) {                             \
    int id = p * 64 + lane; int r = id >> 4, C = id & 15;                     \
    const float* g = gbase + (size_t)r * NIN + (KT) * 128 + C * 8;            \
    s0[p] = *(const float4*)g; s1[p] = *(const float4*)(g + 4);               \
  }
#define T1_SWRITE()                                                           \
  _Pragma("unroll") for (int p = 0; p < 8; ++p) {                             \
    int id = p * 64 + lane; int r = id >> 4, C = id & 15;                     \
    u16x8 h;                                                                  \
    h[0] = f2bf(s0[p].x); h[1] = f2bf(s0[p].y);                               \
    h[2] = f2bf(s0[p].z); h[3] = f2bf(s0[p].w);                               \
    h[4] = f2bf(s1[p].x); h[5] = f2bf(s1[p].y);                               \
    h[6] = f2bf(s1[p].z); h[7] = f2bf(s1[p].w);                               \
    *(u16x8*)(abuf + r * 256 + ((C ^ (r & 7)) << 4)) = h;                     \
  }
#define T1_BLOAD(P, S)                                                        \
  _Pragma("unroll") for (int t = 0; t < 8; ++t)                               \
    P[t] = *(const bf16x8*)(Mf + ((size_t)(t * 64 + Jbase + (S)) * 64 + lane) * 8);

  T1_SLOAD(0);
  T1_SWRITE();
  T1_BLOAD(bx, 0);
#pragma unroll
  for (int s = 0; s < 16; ++s) {
    const int kt = s >> 2, j = s & 3;
    if (j == 0 && kt < 3) { T1_SLOAD(kt + 1); }
    bf16x8 a0, a1;
    {
      int C = j * 4 + lg;
      a0 = *(const bf16x8*)(abuf + lr * 256 + ((C ^ (lr & 7)) << 4));
      a1 = *(const bf16x8*)(abuf + (16 + lr) * 256 + ((C ^ ((16 + lr) & 7)) << 4));
    }
    if (s < 15) { if (s & 1) { T1_BLOAD(bx, s + 1); } else { T1_BLOAD(by, s + 1); } }
#pragma unroll
    for (int t = 0; t < 8; ++t) {
      bf16x8 bcur = (s & 1) ? by[t] : bx[t];
      acc[0][t] = __builtin_amdgcn_mfma_f32_16x16x32_bf16(a0, bcur, acc[0][t], 0, 0, 0);
      acc[1][t] = __builtin_amdgcn_mfma_f32_16x16x32_bf16(a1, bcur, acc[1][t], 0, 0, 0);
    }
    if (j == 3 && kt < 3) { T1_SWRITE(); }
  }

  __syncthreads();                      // (1) abuf done; rbuf overlays
#pragma unroll
  for (int m = 0; m < 2; ++m)
#pragma unroll
    for (int t = 0; t < 8; ++t) {
      int col = t * 16 + lr, row = m * 16 + lg * 4;
      *(f32x4*)&rbuf[((size_t)w * 128 + col) * 36 + row] = acc[m][t];
    }
  __syncthreads();                      // (2)
  // reduce into regs
  {
    int r = tid & 31, cg = tid >> 5;
    float sums[16];
#pragma unroll
    for (int i = 0; i < 16; ++i) {
      int col = cg * 16 + i;
      sums[i] = rbuf[(size_t)col * 36 + r]
              + rbuf[((size_t)128 + col) * 36 + r]
              + rbuf[((size_t)256 + col) * 36 + r]
              + rbuf[((size_t)384 + col) * 36 + r];
    }
    __syncthreads();                    // (3) rbuf reads done; t1s/obuf overlay OK
    u16x8 o1, o2;
#pragma unroll
    for (int i = 0; i < 8; ++i) { o1[i] = f2bf(sums[i]); o2[i] = f2bf(sums[8 + i]); }
    *(u16x8*)(lds + 65536 + r * 256 + (((cg * 2)     ^ (r & 7)) << 4)) = o1;
    *(u16x8*)(lds + 65536 + r * 256 + (((cg * 2 + 1) ^ (r & 7)) << 4)) = o2;
  }
  __syncthreads();                      // (4) t1s visible

  // ---- phase 2: out[row0..+32][:] = input + T1 @ D^T ----
  bf16x8 bq[2][4];
#pragma unroll
  for (int R = 0; R < 2; ++R)
#pragma unroll
    for (int J = 0; J < 4; ++J) {
      int row = R * 16 + lr, cc = J * 4 + lg;
      bq[R][J] = *(const bf16x8*)(lds + 65536 + row * 256 + ((cc ^ (row & 7)) << 4));
    }
  float* obufw = (float*)(lds + w * 8704);   // [32][68]
  bf16x8 xd[4], yd[4];
#define O_DLOAD(P, TTI)                                                       \
  _Pragma("unroll") for (int J = 0; J < 4; ++J)                               \
    P[J] = *(const bf16x8*)(Df + ((size_t)((w * 32 + (TTI)) * 4 + J) * 64 + lane) * 8);

  O_DLOAD(xd, 0);
#pragma unroll
  for (int g = 0; g < 8; ++g) {
#pragma unroll
    for (int tt = 0; tt < 4; ++tt) {
      const int tti = g * 4 + tt;
      if (tti < 31) { if (tti & 1) { O_DLOAD(xd, tti + 1); } else { O_DLOAD(yd, tti + 1); } }
#pragma unroll
      for (int R = 0; R < 2; ++R) {
        f32x4 o = {};
#pragma unroll
        for (int J = 0; J < 4; ++J) {
          bf16x8 d = (tti & 1) ? yd[J] : xd[J];
          o = __builtin_amdgcn_mfma_f32_16x16x32_bf16(d, bq[R][J], o, 0, 0, 0);
        }
        *(f32x4*)&obufw[(R * 16 + lr) * 68 + tt * 16 + lg * 4] = o;
      }
    }
#pragma unroll
    for (int c = 0; c < 8; ++c) {
      int id = c * 64 + lane, r = id >> 4, cc = id & 15;
      f32x4 v = *(const f32x4*)&obufw[r * 68 + cc * 4];
      int grow = row0 + r, gcol = w * 512 + g * 64 + cc * 4;
      float4 inv = *(const float4*)(input + (size_t)grow * NIN + gcol);
      float4 res = { v[0] + inv.x, v[1] + inv.y, v[2] + inv.z, v[3] + inv.w };
      *(float4*)(out + (size_t)grow * NIN + gcol) = res;
    }
  }
}

extern "C" void kernel_launch(void* const* d_in, const int* in_sizes, int n_in,
                              void* d_out, int out_size, void* d_ws, size_t ws_size,
                              hipStream_t stream) {
  const float* input = (const float*)d_in[0];
  const float* U     = (const float*)d_in[1];
  const float* V     = (const float*)d_in[2];
  float* out = (float*)d_out;
  char* ws = (char*)d_ws;

  // workspace layout
  float* mats = (float*)ws;                       // 10 x 128x128 fp32 = 640 KB
  float* G   = mats + 0 * 16384;
  float* G2  = mats + 1 * 16384;
  float* G3  = mats + 2 * 16384;
  float* G4  = mats + 3 * 16384;
  float* G7  = mats + 4 * 16384;
  float* G8  = mats + 5 * 16384;
  float* H12 = mats + 6 * 16384;
  float* H124= mats + 7 * 16384;
  float* H   = mats + 8 * 16384;
  float* G15 = mats + 9 * 16384;
  unsigned short* Mf = (unsigned short*)(ws + 10 * 65536);                // 512 KB frag-order M
  unsigned short* Df = (unsigned short*)(ws + 10 * 65536 + 524288);       // 512 KB frag-order D

  k_prep<<<192, 256, 0, stream>>>(U, V, Mf, G);

  { SOps o = {{ {G,  G,  G2, 0.f, 0.f}, {nullptr,nullptr,nullptr,0.f,0.f}, {nullptr,nullptr,nullptr,0.f,0.f} }};
    k_small<<<64, 256, 0, stream>>>(o); }
  { SOps o = {{ {G2, G2, G4, 0.f, 0.f}, {G2, G, G3, 0.f, 0.f}, {G, G2, H12, 1.f, 1.f} }};
    k_small<<<192, 256, 0, stream>>>(o); }
  { SOps o = {{ {G4, G4, G8, 0.f, 0.f}, {G3, G4, G7, 0.f, 0.f}, {H12, G4, H124, 0.f, 1.f} }};
    k_small<<<192, 256, 0, stream>>>(o); }
  { SOps o = {{ {G7, G8, G15, 0.f, 0.f}, {H124, G8, H, 0.f, 1.f}, {nullptr,nullptr,nullptr,0.f,0.f} }};
    k_small<<<128, 256, 0, stream>>>(o); }

  k_D<<<1024, 256, 0, stream>>>(U, V, H, G15, Df);
  k_main<<<512, 256, 0, stream>>>(input, Mf, Df, out);
}

// Round 9
// 159.532 us; speedup vs baseline: 1.5176x; 1.2264x over previous
//
#include <hip/hip_runtime.h>
#include <hip/hip_bf16.h>
#include <cstdint>
#include <cstddef>

// ---- problem constants ----
#define NIN   2048
#define RANK  64
#define R2    128      // 2*RANK
#define NROWS 16384    // 8*2048 flattened batch*seq rows

typedef __bf16 bf16x8 __attribute__((ext_vector_type(8)));
typedef float  f32x4  __attribute__((ext_vector_type(4)));
typedef unsigned short u16x8 __attribute__((ext_vector_type(8)));

__device__ __forceinline__ unsigned short f2bf(float f) {
  union { float f; unsigned u; } x; x.f = f;
  return (unsigned short)((x.u + 0x7fffu + ((x.u >> 16) & 1u)) >> 16);
}

// ---- small GEMM tile helper: 16x16 tile t of (A + a*I)(B + b*I), fp32 ----
__device__ __forceinline__ void smallGemm(const float* __restrict__ A,
                                          const float* __restrict__ B,
                                          float* __restrict__ O,
                                          float a, float b, int t, int tid) {
  int i = (t >> 3) * 16 + (tid >> 4);
  int j = (t & 7) * 16 + (tid & 15);
  float acc = 0.f;
#pragma unroll 8
  for (int k = 0; k < R2; ++k) {
    float av = A[i * R2 + k]; if (k == i) av += a;
    float bv = B[k * R2 + j]; if (k == j) bv += b;
    acc += av * bv;
  }
  O[i * R2 + j] = acc;
}

// ---- 1) k_prep: 128 blocks x 512 thr. Blocks 0..63: Mf (frag-order).
//      Blocks 64..127: G = J*(M^T M) tile, 2-way K-split + LDS reduce.
// Mf chunk CI = (t*64 + J)*64 + lane holds M[t*16 + (lane&15)][J*32 + (lane>>4)*8 + e]
__global__ __launch_bounds__(512) void k_prep(const float* __restrict__ U,
                                              const float* __restrict__ V,
                                              unsigned short* __restrict__ Mf,
                                              float* __restrict__ G) {
  __shared__ float red[512];
  int b = blockIdx.x, tid = threadIdx.x;
  if (b < 64) {
    int CI = b * 512 + tid;                 // 0..32767
    int lane = CI & 63, J = (CI >> 6) & 63, t = CI >> 12;
    int n = t * 16 + (lane & 15);
    int k0 = J * 32 + (lane >> 4) * 8;
    const float* src = (n < RANK) ? (U + n) : (V + (n - RANK));
    u16x8 h;
#pragma unroll
    for (int e = 0; e < 8; ++e) h[e] = f2bf(src[(size_t)(k0 + e) * RANK]);
    *(u16x8*)(Mf + (size_t)CI * 8) = h;
  } else {
    int tile = b - 64;                      // 0..63
    int bi = tile >> 3, bj = tile & 7;
    int sub = tid >> 8, t256 = tid & 255;
    int ty = t256 >> 4, tx = t256 & 15;
    int i = bi * 16 + ty, j = bj * 16 + tx;
    const float* Ai = (i < RANK) ? (U + i) : (V + (i - RANK));
    const float* Aj = (j < RANK) ? (U + j) : (V + (j - RANK));
    int k0 = sub * 1024;
    float acc = 0.f;
#pragma unroll 8
    for (int k = k0; k < k0 + 1024; ++k) acc += Ai[(size_t)k * RANK] * Aj[(size_t)k * RANK];
    red[tid] = acc;
    __syncthreads();
    if (sub == 0) {
      float s = red[t256] + red[256 + t256];
      if (i < RANK) G[(i + RANK) * R2 + j] = -s;
      else          G[(i - RANK) * R2 + j] =  s;
    }
  }
}

// ---- 2) generic small 128x128 GEMM launch: O = (A + a*I)(B + b*I), fp32 ----
struct SOp { const float* A; const float* B; float* O; float a, b; };
struct SOps { SOp op[3]; };
__global__ void k_small(SOps ops) {
  SOp o = ops.op[blockIdx.x >> 6];     // 64 blocks per op
  smallGemm(o.A, o.B, o.O, o.a, o.b, blockIdx.x & 63, threadIdx.x);
}

// ---- 3) Df = bf16( M * ((2H - G15) * J) ) in FRAG-ORDER ----
// Df chunk CI = (t*4 + J)*64 + lane holds D[t*16 + (lane&15)][J*32 + (lane>>4)*8 + e]
__global__ void k_D(const float* __restrict__ U, const float* __restrict__ V,
                    const float* __restrict__ H, const float* __restrict__ G15,
                    unsigned short* __restrict__ Df) {
  int idx = blockIdx.x * 256 + threadIdx.x;  // i*128 + j, i < 2048
  int i = idx >> 7, j = idx & 127;
  int jj = (j < RANK) ? (j + RANK) : (j - RANK);
  float sgn = (j < RANK) ? -1.f : 1.f;
  float acc = 0.f;
#pragma unroll 8
  for (int k = 0; k < R2; ++k) {
    float m = (k < RANK) ? U[(size_t)i * RANK + k] : V[(size_t)i * RANK + (k - RANK)];
    float t = 2.f * H[k * R2 + jj] - G15[k * R2 + jj];
    acc += m * (sgn * t);
  }
  int t_ = i >> 4, lr = i & 15;
  int J = j >> 5, lg = (j >> 3) & 3, e = j & 7;
  size_t CI = (size_t)(t_ * 4 + J) * 64 + lg * 16 + lr;
  Df[CI * 8 + e] = f2bf(acc);
}

// ---- 4) k_T1: T1bf = bf16(input @ M), 512 blocks of 32 rows + 64 G2-blocks.
// Wave w owns K-range [w*512,(w+1)*512). Input staged via per-wave swizzled LDS;
// M frags contiguous from Mf. Blocks 512..575 compute G2 = G*G (s1 fold).
__global__ __launch_bounds__(256) void k_T1(const float* __restrict__ input,
                                            const unsigned short* __restrict__ Mf,
                                            unsigned short* __restrict__ T1bf,
                                            const float* __restrict__ G,
                                            float* __restrict__ G2) {
  __shared__ __align__(16) unsigned char lds[73728];  // abuf[w] 8KB x4, then rbuf[4][128][36] f32
  if (blockIdx.x >= 512) {                  // s1 fold: G2 = G*G
    smallGemm(G, G, G2, 0.f, 0.f, blockIdx.x - 512, threadIdx.x);
    return;
  }
  const int tid = threadIdx.x, lane = tid & 63, w = tid >> 6;
  const int lr = lane & 15, lg = lane >> 4;
  const int row0 = blockIdx.x * 32;
  unsigned char* abuf = lds + w * 8192;
  float* rbuf = (float*)lds;

  f32x4 acc[2][8] = {};
  const float* gbase = input + (size_t)row0 * NIN + w * 512;
  const int Jbase = w * 16;
  float4 s0[8], s1[8];
  bf16x8 bx[8], by[8];

#define T1_SLOAD(KT)                                                          \
  _Pragma("unroll") for (int p = 0; p < 8; ++p) {                             \
    int id = p * 64 + lane; int r = id >> 4, C = id & 15;                     \
    const float* g = gbase + (size_t)r * NIN + (KT) * 128 + C * 8;            \
    s0[p] = *(const float4*)g; s1[p] = *(const float4*)(g + 4);               \
  }
#define T1_SWRITE()                                                           \
  _Pragma("unroll") for (int p = 0; p < 8; ++p) {                             \
    int id = p * 64 + lane; int r = id >> 4, C = id & 15;                     \
    u16x8 h;                                                                  \
    h[0] = f2bf(s0[p].x); h[1] = f2bf(s0[p].y);                               \
    h[2] = f2bf(s0[p].z); h[3] = f2bf(s0[p].w);                               \
    h[4] = f2bf(s1[p].x); h[5] = f2bf(s1[p].y);                               \
    h[6] = f2bf(s1[p].z); h[7] = f2bf(s1[p].w);                               \
    *(u16x8*)(abuf + r * 256 + ((C ^ (r & 7)) << 4)) = h;                     \
  }
#define T1_BLOAD(P, S)                                                        \
  _Pragma("unroll") for (int t = 0; t < 8; ++t)                               \
    P[t] = *(const bf16x8*)(Mf + ((size_t)(t * 64 + Jbase + (S)) * 64 + lane) * 8);

  T1_SLOAD(0);
  T1_SWRITE();
  T1_BLOAD(bx, 0);
#pragma unroll
  for (int s = 0; s < 16; ++s) {
    const int kt = s >> 2, j = s & 3;
    if (j == 0 && kt < 3) { T1_SLOAD(kt + 1); }
    bf16x8 a0, a1;
    {
      int C = j * 4 + lg;
      a0 = *(const bf16x8*)(abuf + lr * 256 + ((C ^ (lr & 7)) << 4));
      a1 = *(const bf16x8*)(abuf + (16 + lr) * 256 + ((C ^ ((16 + lr) & 7)) << 4));
    }
    if (s < 15) { if (s & 1) { T1_BLOAD(bx, s + 1); } else { T1_BLOAD(by, s + 1); } }
#pragma unroll
    for (int t = 0; t < 8; ++t) {
      bf16x8 bcur = (s & 1) ? by[t] : bx[t];
      acc[0][t] = __builtin_amdgcn_mfma_f32_16x16x32_bf16(a0, bcur, acc[0][t], 0, 0, 0);
      acc[1][t] = __builtin_amdgcn_mfma_f32_16x16x32_bf16(a1, bcur, acc[1][t], 0, 0, 0);
    }
    if (j == 3 && kt < 3) { T1_SWRITE(); }
  }

  __syncthreads();   // abuf done; rbuf overlays
#pragma unroll
  for (int m = 0; m < 2; ++m)
#pragma unroll
    for (int t = 0; t < 8; ++t) {
      int col = t * 16 + lr, row = m * 16 + lg * 4;
      *(f32x4*)&rbuf[((size_t)w * 128 + col) * 36 + row] = acc[m][t];
    }
  __syncthreads();
  {
    int r = tid & 31, cg = tid >> 5;
    u16x8 o1, o2;
#pragma unroll
    for (int i = 0; i < 16; ++i) {
      int col = cg * 16 + i;
      float s = rbuf[(size_t)col * 36 + r]
              + rbuf[((size_t)128 + col) * 36 + r]
              + rbuf[((size_t)256 + col) * 36 + r]
              + rbuf[((size_t)384 + col) * 36 + r];
      if (i < 8) o1[i] = f2bf(s); else o2[i - 8] = f2bf(s);
    }
    unsigned short* dst = T1bf + (size_t)(row0 + r) * R2 + cg * 16;
    *(u16x8*)dst = o1;
    *(u16x8*)(dst + 8) = o2;
  }
}

// ---- 5) k_OUT: out = input + T1 @ D^T. 512 blocks x 256 thr; 32 rows x 2048 cols.
// Wave w owns cols [w*512,(w+1)*512). T1 frags persistent in regs; Df streamed coalesced;
// epilogue transposed through per-wave LDS so input/out accesses are contiguous. No barriers.
__global__ __launch_bounds__(256) void k_OUT(const float* __restrict__ input,
                                             const unsigned short* __restrict__ T1bf,
                                             const unsigned short* __restrict__ Df,
                                             float* __restrict__ out) {
  __shared__ float obuf[4][32][132];   // per-wave [32 rows][128 cols + pad4]
  const int tid = threadIdx.x, lane = tid & 63, w = tid >> 6;
  const int lr = lane & 15, lg = lane >> 4;
  const int row0 = blockIdx.x * 32;

  // persistent T1 B-frags: bq[R][J] — lane holds T1[row0+R*16+lr][J*32+lg*8..+8]
  bf16x8 bq[2][4];
#pragma unroll
  for (int R = 0; R < 2; ++R)
#pragma unroll
    for (int J = 0; J < 4; ++J)
      bq[R][J] = *(const bf16x8*)(T1bf + (size_t)(row0 + R * 16 + lr) * R2 + J * 32 + lg * 8);

  bf16x8 xd[4], yd[4];
#define O_DLOAD(P, TTI)                                                       \
  _Pragma("unroll") for (int J = 0; J < 4; ++J)                               \
    P[J] = *(const bf16x8*)(Df + ((size_t)((w * 32 + (TTI)) * 4 + J) * 64 + lane) * 8);

  O_DLOAD(xd, 0);
#pragma unroll
  for (int g = 0; g < 4; ++g) {
#pragma unroll
    for (int tt = 0; tt < 8; ++tt) {
      const int tti = g * 8 + tt;
      if (tti < 31) { if (tti & 1) { O_DLOAD(xd, tti + 1); } else { O_DLOAD(yd, tti + 1); } }
#pragma unroll
      for (int R = 0; R < 2; ++R) {
        f32x4 o = {};
#pragma unroll
        for (int J = 0; J < 4; ++J) {
          bf16x8 d = (tti & 1) ? yd[J] : xd[J];
          o = __builtin_amdgcn_mfma_f32_16x16x32_bf16(d, bq[R][J], o, 0, 0, 0);
        }
        *(f32x4*)&obuf[w][R * 16 + lr][tt * 16 + lg * 4] = o;
      }
    }
#pragma unroll
    for (int c = 0; c < 16; ++c) {
      int id = c * 64 + lane;
      int r = id >> 5, cc = id & 31;
      f32x4 v = *(const f32x4*)&obuf[w][r][cc * 4];
      int grow = row0 + r, gcol = w * 512 + g * 128 + cc * 4;
      float4 inv = *(const float4*)(input + (size_t)grow * NIN + gcol);
      float4 res = { v[0] + inv.x, v[1] + inv.y, v[2] + inv.z, v[3] + inv.w };
      *(float4*)(out + (size_t)grow * NIN + gcol) = res;
    }
  }
}

extern "C" void kernel_launch(void* const* d_in, const int* in_sizes, int n_in,
                              void* d_out, int out_size, void* d_ws, size_t ws_size,
                              hipStream_t stream) {
  const float* input = (const float*)d_in[0];
  const float* U     = (const float*)d_in[1];
  const float* V     = (const float*)d_in[2];
  float* out = (float*)d_out;
  char* ws = (char*)d_ws;

  // workspace layout
  float* mats = (float*)ws;                       // 10 x 128x128 fp32 = 640 KB
  float* G   = mats + 0 * 16384;
  float* G2  = mats + 1 * 16384;
  float* G3  = mats + 2 * 16384;
  float* G4  = mats + 3 * 16384;
  float* G7  = mats + 4 * 16384;
  float* G8  = mats + 5 * 16384;
  float* H12 = mats + 6 * 16384;
  float* H124= mats + 7 * 16384;
  float* H   = mats + 8 * 16384;
  float* G15 = mats + 9 * 16384;
  unsigned short* Mf   = (unsigned short*)(ws + 10 * 65536);              // 512 KB frag-order M
  unsigned short* Df   = (unsigned short*)(ws + 10 * 65536 + 524288);     // 512 KB frag-order D
  unsigned short* T1bf = (unsigned short*)(ws + 10 * 65536 + 2 * 524288); // 4 MB

  k_prep<<<128, 512, 0, stream>>>(U, V, Mf, G);
  k_T1<<<576, 256, 0, stream>>>(input, Mf, T1bf, G, G2);   // + s1 fold (G2)

  { SOps o = {{ {G2, G2, G4, 0.f, 0.f}, {G2, G, G3, 0.f, 0.f}, {G, G2, H12, 1.f, 1.f} }};
    k_small<<<192, 256, 0, stream>>>(o); }
  { SOps o = {{ {G4, G4, G8, 0.f, 0.f}, {G3, G4, G7, 0.f, 0.f}, {H12, G4, H124, 0.f, 1.f} }};
    k_small<<<192, 256, 0, stream>>>(o); }
  { SOps o = {{ {G7, G8, G15, 0.f, 0.f}, {H124, G8, H, 0.f, 1.f}, {nullptr,nullptr,nullptr,0.f,0.f} }};
    k_small<<<128, 256, 0, stream>>>(o); }

  k_D<<<1024, 256, 0, stream>>>(U, V, H, G15, Df);
  k_OUT<<<512, 256, 0, stream>>>(input, T1bf, Df, out);
}

// Round 10
// 141.276 us; speedup vs baseline: 1.7137x; 1.1292x over previous
//
#include <hip/hip_runtime.h>
#include <hip/hip_bf16.h>
#include <cstdint>
#include <cstddef>

// ---- problem constants ----
#define NIN   2048
#define RANK  64
#define R2    128      // 2*RANK
#define NROWS 16384    // 8*2048 flattened batch*seq rows

typedef __bf16 bf16x8 __attribute__((ext_vector_type(8)));
typedef float  f32x4  __attribute__((ext_vector_type(4)));
typedef unsigned short u16x8 __attribute__((ext_vector_type(8)));

__device__ __forceinline__ unsigned short f2bf(float f) {
  union { float f; unsigned u; } x; x.f = f;
  return (unsigned short)((x.u + 0x7fffu + ((x.u >> 16) & 1u)) >> 16);
}

// ---- small GEMM tile helper: 16x16 tile t of (A + a*I)(B + b*I), fp32 ----
__device__ __forceinline__ void smallGemm(const float* __restrict__ A,
                                          const float* __restrict__ B,
                                          float* __restrict__ O,
                                          float a, float b, int t, int tid) {
  int i = (t >> 3) * 16 + (tid >> 4);
  int j = (t & 7) * 16 + (tid & 15);
  float acc = 0.f;
#pragma unroll 8
  for (int k = 0; k < R2; ++k) {
    float av = A[i * R2 + k]; if (k == i) av += a;
    float bv = B[k * R2 + j]; if (k == j) bv += b;
    acc += av * bv;
  }
  O[i * R2 + j] = acc;
}

// ---- 1) k_prep: 192 blocks x 512 thr.
//  blocks 0..63:   Mf (frag-order over K=2048; B-operand of k_T1)
//  blocks 64..127: G = J*(M^T M) tile, 2-way K-split + LDS reduce, 4 accumulators
//  blocks 128..191: Mrf (M rows in Df-style frag-order; A-operand of k_OUT)
__global__ __launch_bounds__(512) void k_prep(const float* __restrict__ U,
                                              const float* __restrict__ V,
                                              unsigned short* __restrict__ Mf,
                                              unsigned short* __restrict__ Mrf,
                                              float* __restrict__ G) {
  __shared__ float red[512];
  int b = blockIdx.x, tid = threadIdx.x;
  if (b < 64) {
    int CI = b * 512 + tid;                 // 0..32767
    int lane = CI & 63, J = (CI >> 6) & 63, t = CI >> 12;
    int n = t * 16 + (lane & 15);
    int k0 = J * 32 + (lane >> 4) * 8;
    const float* src = (n < RANK) ? (U + n) : (V + (n - RANK));
    u16x8 h;
#pragma unroll
    for (int e = 0; e < 8; ++e) h[e] = f2bf(src[(size_t)(k0 + e) * RANK]);
    *(u16x8*)(Mf + (size_t)CI * 8) = h;
  } else if (b < 128) {
    int tile = b - 64;                      // 0..63
    int bi = tile >> 3, bj = tile & 7;
    int sub = tid >> 8, t256 = tid & 255;
    int ty = t256 >> 4, tx = t256 & 15;
    int i = bi * 16 + ty, j = bj * 16 + tx;
    const float* Ai = (i < RANK) ? (U + i) : (V + (i - RANK));
    const float* Aj = (j < RANK) ? (U + j) : (V + (j - RANK));
    int k0 = sub * 1024;
    float p0 = 0.f, p1 = 0.f, p2 = 0.f, p3 = 0.f;
#pragma unroll 4
    for (int k = k0; k < k0 + 1024; k += 4) {
      p0 += Ai[(size_t)k * RANK]       * Aj[(size_t)k * RANK];
      p1 += Ai[(size_t)(k + 1) * RANK] * Aj[(size_t)(k + 1) * RANK];
      p2 += Ai[(size_t)(k + 2) * RANK] * Aj[(size_t)(k + 2) * RANK];
      p3 += Ai[(size_t)(k + 3) * RANK] * Aj[(size_t)(k + 3) * RANK];
    }
    red[tid] = (p0 + p1) + (p2 + p3);
    __syncthreads();
    if (sub == 0) {
      float s = red[t256] + red[256 + t256];
      if (i < RANK) G[(i + RANK) * R2 + j] = -s;
      else          G[(i - RANK) * R2 + j] =  s;
    }
  } else {
    // Mrf chunk CI = (t_*4 + J)*64 + lg*16 + lr holds M[t_*16+lr][J*32+lg*8+e]
    int CI = (b - 128) * 512 + tid;         // 0..32767
    int lane = CI & 63, rest = CI >> 6;
    int lr = lane & 15, lg = lane >> 4;
    int J = rest & 3, t_ = rest >> 2;
    int i = t_ * 16 + lr, j0 = J * 32 + lg * 8;
    const float* src = (j0 < RANK) ? (U + (size_t)i * RANK + j0)
                                   : (V + (size_t)i * RANK + (j0 - RANK));
    float4 f0 = *(const float4*)src, f1 = *(const float4*)(src + 4);
    u16x8 h;
    h[0] = f2bf(f0.x); h[1] = f2bf(f0.y); h[2] = f2bf(f0.z); h[3] = f2bf(f0.w);
    h[4] = f2bf(f1.x); h[5] = f2bf(f1.y); h[6] = f2bf(f1.z); h[7] = f2bf(f1.w);
    *(u16x8*)(Mrf + (size_t)CI * 8) = h;
  }
}

// ---- 2) generic small 128x128 GEMM launch: O = (A + a*I)(B + b*I), fp32 ----
struct SOp { const float* A; const float* B; float* O; float a, b; };
struct SOps { SOp op[3]; };
__global__ void k_small(SOps ops) {
  SOp o = ops.op[blockIdx.x >> 6];     // 64 blocks per op
  smallGemm(o.A, o.B, o.O, o.a, o.b, blockIdx.x & 63, threadIdx.x);
}

// ---- 3) k_T1: T1bf = bf16(input @ M), 512 blocks of 32 rows + 64 G2-blocks.
// Wave w owns K-range [w*512,(w+1)*512). Input staged via per-wave swizzled LDS;
// M frags contiguous from Mf. Blocks 512..575 compute G2 = G*G (s1 fold).
__global__ __launch_bounds__(256) void k_T1(const float* __restrict__ input,
                                            const unsigned short* __restrict__ Mf,
                                            unsigned short* __restrict__ T1bf,
                                            const float* __restrict__ G,
                                            float* __restrict__ G2) {
  __shared__ __align__(16) unsigned char lds[73728];  // abuf[w] 8KB x4, then rbuf[4][128][36] f32
  if (blockIdx.x >= 512) {                  // s1 fold: G2 = G*G
    smallGemm(G, G, G2, 0.f, 0.f, blockIdx.x - 512, threadIdx.x);
    return;
  }
  const int tid = threadIdx.x, lane = tid & 63, w = tid >> 6;
  const int lr = lane & 15, lg = lane >> 4;
  const int row0 = blockIdx.x * 32;
  unsigned char* abuf = lds + w * 8192;
  float* rbuf = (float*)lds;

  f32x4 acc[2][8] = {};
  const float* gbase = input + (size_t)row0 * NIN + w * 512;
  const int Jbase = w * 16;
  float4 s0[8], s1[8];
  bf16x8 bx[8], by[8];

#define T1_SLOAD(KT)                                                          \
  _Pragma("unroll") for (int p = 0; p < 8; ++p) {                             \
    int id = p * 64 + lane; int r = id >> 4, C = id & 15;                     \
    const float* g = gbase + (size_t)r * NIN + (KT) * 128 + C * 8;            \
    s0[p] = *(const float4*)g; s1[p] = *(const float4*)(g + 4);               \
  }
#define T1_SWRITE()                                                           \
  _Pragma("unroll") for (int p = 0; p < 8; ++p) {                             \
    int id = p * 64 + lane; int r = id >> 4, C = id & 15;                     \
    u16x8 h;                                                                  \
    h[0] = f2bf(s0[p].x); h[1] = f2bf(s0[p].y);                               \
    h[2] = f2bf(s0[p].z); h[3] = f2bf(s0[p].w);                               \
    h[4] = f2bf(s1[p].x); h[5] = f2bf(s1[p].y);                               \
    h[6] = f2bf(s1[p].z); h[7] = f2bf(s1[p].w);                               \
    *(u16x8*)(abuf + r * 256 + ((C ^ (r & 7)) << 4)) = h;                     \
  }
#define T1_BLOAD(P, S)                                                        \
  _Pragma("unroll") for (int t = 0; t < 8; ++t)                               \
    P[t] = *(const bf16x8*)(Mf + ((size_t)(t * 64 + Jbase + (S)) * 64 + lane) * 8);

  T1_SLOAD(0);
  T1_SWRITE();
  T1_BLOAD(bx, 0);
#pragma unroll
  for (int s = 0; s < 16; ++s) {
    const int kt = s >> 2, j = s & 3;
    if (j == 0 && kt < 3) { T1_SLOAD(kt + 1); }
    bf16x8 a0, a1;
    {
      int C = j * 4 + lg;
      a0 = *(const bf16x8*)(abuf + lr * 256 + ((C ^ (lr & 7)) << 4));
      a1 = *(const bf16x8*)(abuf + (16 + lr) * 256 + ((C ^ ((16 + lr) & 7)) << 4));
    }
    if (s < 15) { if (s & 1) { T1_BLOAD(bx, s + 1); } else { T1_BLOAD(by, s + 1); } }
#pragma unroll
    for (int t = 0; t < 8; ++t) {
      bf16x8 bcur = (s & 1) ? by[t] : bx[t];
      acc[0][t] = __builtin_amdgcn_mfma_f32_16x16x32_bf16(a0, bcur, acc[0][t], 0, 0, 0);
      acc[1][t] = __builtin_amdgcn_mfma_f32_16x16x32_bf16(a1, bcur, acc[1][t], 0, 0, 0);
    }
    if (j == 3 && kt < 3) { T1_SWRITE(); }
  }

  __syncthreads();   // abuf done; rbuf overlays
#pragma unroll
  for (int m = 0; m < 2; ++m)
#pragma unroll
    for (int t = 0; t < 8; ++t) {
      int col = t * 16 + lr, row = m * 16 + lg * 4;
      *(f32x4*)&rbuf[((size_t)w * 128 + col) * 36 + row] = acc[m][t];
    }
  __syncthreads();
  {
    int r = tid & 31, cg = tid >> 5;
    u16x8 o1, o2;
#pragma unroll
    for (int i = 0; i < 16; ++i) {
      int col = cg * 16 + i;
      float s = rbuf[(size_t)col * 36 + r]
              + rbuf[((size_t)128 + col) * 36 + r]
              + rbuf[((size_t)256 + col) * 36 + r]
              + rbuf[((size_t)384 + col) * 36 + r];
      if (i < 8) o1[i] = f2bf(s); else o2[i - 8] = f2bf(s);
    }
    unsigned short* dst = T1bf + (size_t)(row0 + r) * R2 + cg * 16;
    *(u16x8*)dst = o1;
    *(u16x8*)(dst + 8) = o2;
  }
}

// ---- 4) k_OUT: out = input + T2 @ M^T, with T2 = T1 @ C^T computed in-block.
// C[k][j] = sgn(j)*(2H - G15)[k][jj(j)]  (the verified k_D math, minus the M multiply).
// 512 blocks x 256 thr; 32 rows x 2048 cols. Wave w owns cols [w*512,(w+1)*512).
// LDS: [0,67584) = cbuf (prologue, 32KB bf16 swz) then obuf [4][32][132] f32 (main);
//      [67584,75776) = t2buf bf16 [32][128] swz.
__global__ __launch_bounds__(256) void k_OUT(const float* __restrict__ input,
                                             const unsigned short* __restrict__ T1bf,
                                             const float* __restrict__ Hm,
                                             const float* __restrict__ G15m,
                                             const unsigned short* __restrict__ Mrf,
                                             float* __restrict__ out) {
  __shared__ __align__(16) unsigned char lds[75776];
  unsigned char* cbuf = lds;
  unsigned char* t2buf = lds + 67584;
  const int tid = threadIdx.x, lane = tid & 63, w = tid >> 6;
  const int lr = lane & 15, lg = lane >> 4;
  const int row0 = blockIdx.x * 32;

  // ---- prologue A: cbuf[k][j-granule swz] = C row-major bf16 ----
#pragma unroll
  for (int it = 0; it < 8; ++it) {
    int id = it * 256 + tid;                 // chunk 0..2047
    int k = id >> 4, j8 = id & 15, j0 = j8 * 8;
    int jj0 = (j0 < RANK) ? j0 + RANK : j0 - RANK;
    float sgn = (j0 < RANK) ? -1.f : 1.f;
    const float* hp = Hm + k * R2 + jj0;
    const float* gp = G15m + k * R2 + jj0;
    float4 h0 = *(const float4*)hp, h1 = *(const float4*)(hp + 4);
    float4 g0 = *(const float4*)gp, g1 = *(const float4*)(gp + 4);
    u16x8 cv;
    cv[0] = f2bf(sgn * (2.f * h0.x - g0.x));
    cv[1] = f2bf(sgn * (2.f * h0.y - g0.y));
    cv[2] = f2bf(sgn * (2.f * h0.z - g0.z));
    cv[3] = f2bf(sgn * (2.f * h0.w - g0.w));
    cv[4] = f2bf(sgn * (2.f * h1.x - g1.x));
    cv[5] = f2bf(sgn * (2.f * h1.y - g1.y));
    cv[6] = f2bf(sgn * (2.f * h1.z - g1.z));
    cv[7] = f2bf(sgn * (2.f * h1.w - g1.w));
    *(u16x8*)(cbuf + k * 256 + ((j8 ^ (k & 7)) << 4)) = cv;
  }
  // T1 frags (B operand of T2-mfma): lane lr -> T1 row row0+R*16+lr
  bf16x8 t1f[2][4];
#pragma unroll
  for (int R = 0; R < 2; ++R)
#pragma unroll
    for (int J = 0; J < 4; ++J)
      t1f[R][J] = *(const bf16x8*)(T1bf + (size_t)(row0 + R * 16 + lr) * R2 + J * 32 + lg * 8);
  __syncthreads();                           // cbuf ready

  // ---- prologue B: T2[r][kc] = sum_j T1[r][j] C[kc][j]; wave w: kc-tiles {2w,2w+1} ----
#pragma unroll
  for (int kk = 0; kk < 2; ++kk) {
    int kct = w * 2 + kk;
    int kc = kct * 16 + lr;                  // C row this lane supplies
    f32x4 a2[2] = {};
#pragma unroll
    for (int jkt = 0; jkt < 4; ++jkt) {
      bf16x8 cf = *(const bf16x8*)(cbuf + kc * 256 + (((jkt * 4 + lg) ^ (kc & 7)) << 4));
#pragma unroll
      for (int R = 0; R < 2; ++R)
        a2[R] = __builtin_amdgcn_mfma_f32_16x16x32_bf16(cf, t1f[R][jkt], a2[R], 0, 0, 0);
    }
    // acc layout: col=lr -> r_local, row=lg*4+e -> kc = kct*16+lg*4+e
#pragma unroll
    for (int R = 0; R < 2; ++R) {
      int r = R * 16 + lr;
      ushort4 p;
      p.x = f2bf(a2[R][0]); p.y = f2bf(a2[R][1]);
      p.z = f2bf(a2[R][2]); p.w = f2bf(a2[R][3]);
      int gran = kct * 2 + (lg >> 1), off = (lg & 1) * 8;
      *(ushort4*)(t2buf + r * 256 + ((gran ^ (r & 7)) << 4) + off) = p;
    }
  }
  __syncthreads();                           // t2buf ready (all waves)

  // bq = T2 frags: lane lr -> row R*16+lr, k-slice J*32+lg*8
  bf16x8 bq[2][4];
#pragma unroll
  for (int R = 0; R < 2; ++R)
#pragma unroll
    for (int J = 0; J < 4; ++J) {
      int row = R * 16 + lr;
      bq[R][J] = *(const bf16x8*)(t2buf + row * 256 + (((J * 4 + lg) ^ (row & 7)) << 4));
    }

  // ---- main loop: identical to verified round-9 k_OUT, Mrf as A-operand ----
  float* obufw = (float*)lds + (size_t)w * 32 * 132;   // per-wave [32][132]
  bf16x8 xd[4], yd[4];
#define O_DLOAD(P, TTI)                                                       \
  _Pragma("unroll") for (int J = 0; J < 4; ++J)                               \
    P[J] = *(const bf16x8*)(Mrf + ((size_t)((w * 32 + (TTI)) * 4 + J) * 64 + lane) * 8);

  O_DLOAD(xd, 0);
#pragma unroll
  for (int g = 0; g < 4; ++g) {
#pragma unroll
    for (int tt = 0; tt < 8; ++tt) {
      const int tti = g * 8 + tt;
      if (tti < 31) { if (tti & 1) { O_DLOAD(xd, tti + 1); } else { O_DLOAD(yd, tti + 1); } }
#pragma unroll
      for (int R = 0; R < 2; ++R) {
        f32x4 o = {};
#pragma unroll
        for (int J = 0; J < 4; ++J) {
          bf16x8 d = (tti & 1) ? yd[J] : xd[J];
          o = __builtin_amdgcn_mfma_f32_16x16x32_bf16(d, bq[R][J], o, 0, 0, 0);
        }
        *(f32x4*)&obufw[(R * 16 + lr) * 132 + tt * 16 + lg * 4] = o;
      }
    }
#pragma unroll
    for (int c = 0; c < 16; ++c) {
      int id = c * 64 + lane;
      int r = id >> 5, cc = id & 31;
      f32x4 v = *(const f32x4*)&obufw[r * 132 + cc * 4];
      int grow = row0 + r, gcol = w * 512 + g * 128 + cc * 4;
      float4 inv = *(const float4*)(input + (size_t)grow * NIN + gcol);
      float4 res = { v[0] + inv.x, v[1] + inv.y, v[2] + inv.z, v[3] + inv.w };
      *(float4*)(out + (size_t)grow * NIN + gcol) = res;
    }
  }
}

extern "C" void kernel_launch(void* const* d_in, const int* in_sizes, int n_in,
                              void* d_out, int out_size, void* d_ws, size_t ws_size,
                              hipStream_t stream) {
  const float* input = (const float*)d_in[0];
  const float* U     = (const float*)d_in[1];
  const float* V     = (const float*)d_in[2];
  float* out = (float*)d_out;
  char* ws = (char*)d_ws;

  // workspace layout
  float* mats = (float*)ws;                       // 10 x 128x128 fp32 = 640 KB
  float* G   = mats + 0 * 16384;
  float* G2  = mats + 1 * 16384;
  float* G3  = mats + 2 * 16384;
  float* G4  = mats + 3 * 16384;
  float* G7  = mats + 4 * 16384;
  float* G8  = mats + 5 * 16384;
  float* H12 = mats + 6 * 16384;
  float* H124= mats + 7 * 16384;
  float* H   = mats + 8 * 16384;
  float* G15 = mats + 9 * 16384;
  unsigned short* Mf   = (unsigned short*)(ws + 10 * 65536);              // 512 KB frag-order M (K=2048)
  unsigned short* Mrf  = (unsigned short*)(ws + 10 * 65536 + 524288);     // 512 KB frag-order M rows (K=128)
  unsigned short* T1bf = (unsigned short*)(ws + 10 * 65536 + 2 * 524288); // 4 MB

  k_prep<<<192, 512, 0, stream>>>(U, V, Mf, Mrf, G);
  k_T1<<<576, 256, 0, stream>>>(input, Mf, T1bf, G, G2);   // + s1 fold (G2)

  { SOps o = {{ {G2, G2, G4, 0.f, 0.f}, {G2, G, G3, 0.f, 0.f}, {G, G2, H12, 1.f, 1.f} }};
    k_small<<<192, 256, 0, stream>>>(o); }
  { SOps o = {{ {G4, G4, G8, 0.f, 0.f}, {G3, G4, G7, 0.f, 0.f}, {H12, G4, H124, 0.f, 1.f} }};
    k_small<<<192, 256, 0, stream>>>(o); }
  { SOps o = {{ {G7, G8, G15, 0.f, 0.f}, {H124, G8, H, 0.f, 1.f}, {nullptr,nullptr,nullptr,0.f,0.f} }};
    k_small<<<128, 256, 0, stream>>>(o); }

  k_OUT<<<512, 256, 0, stream>>>(input, T1bf, H, G15, Mrf, out);
}

// Round 11
// 138.729 us; speedup vs baseline: 1.7451x; 1.0184x over previous
//
#include <hip/hip_runtime.h>
#include <hip/hip_bf16.h>
#include <cstdint>
#include <cstddef>

// ---- problem constants ----
#define NIN   2048
#define RANK  64
#define R2    128      // 2*RANK
#define NROWS 16384    // 8*2048 flattened batch*seq rows

typedef __bf16 bf16x8 __attribute__((ext_vector_type(8)));
typedef float  f32x4  __attribute__((ext_vector_type(4)));
typedef unsigned short u16x8 __attribute__((ext_vector_type(8)));

__device__ __forceinline__ unsigned short f2bf(float f) {
  union { float f; unsigned u; } x; x.f = f;
  return (unsigned short)((x.u + 0x7fffu + ((x.u >> 16) & 1u)) >> 16);
}

// ---- small GEMM tile helper: 16x16 tile t of (A + a*I)(B + b*I), fp32 ----
__device__ __forceinline__ void smallGemm(const float* __restrict__ A,
                                          const float* __restrict__ B,
                                          float* __restrict__ O,
                                          float a, float b, int t, int tid) {
  int i = (t >> 3) * 16 + (tid >> 4);
  int j = (t & 7) * 16 + (tid & 15);
  float acc = 0.f;
#pragma unroll 8
  for (int k = 0; k < R2; ++k) {
    float av = A[i * R2 + k]; if (k == i) av += a;
    float bv = B[k * R2 + j]; if (k == j) bv += b;
    acc += av * bv;
  }
  O[i * R2 + j] = acc;
}

// ---- 1) k_prep: 192 blocks x 512 thr.
//  blocks 0..63:   Mf (frag-order over K=2048; B-operand of k_T1)
//  blocks 64..127: G = J*(M^T M) tile, 2-way K-split + LDS reduce, 4 accumulators
//  blocks 128..191: Mrf (M rows in frag-order; A-operand of k_OUT)
__global__ __launch_bounds__(512) void k_prep(const float* __restrict__ U,
                                              const float* __restrict__ V,
                                              unsigned short* __restrict__ Mf,
                                              unsigned short* __restrict__ Mrf,
                                              float* __restrict__ G) {
  __shared__ float red[512];
  int b = blockIdx.x, tid = threadIdx.x;
  if (b < 64) {
    int CI = b * 512 + tid;                 // 0..32767
    int lane = CI & 63, J = (CI >> 6) & 63, t = CI >> 12;
    int n = t * 16 + (lane & 15);
    int k0 = J * 32 + (lane >> 4) * 8;
    const float* src = (n < RANK) ? (U + n) : (V + (n - RANK));
    u16x8 h;
#pragma unroll
    for (int e = 0; e < 8; ++e) h[e] = f2bf(src[(size_t)(k0 + e) * RANK]);
    *(u16x8*)(Mf + (size_t)CI * 8) = h;
  } else if (b < 128) {
    int tile = b - 64;                      // 0..63
    int bi = tile >> 3, bj = tile & 7;
    int sub = tid >> 8, t256 = tid & 255;
    int ty = t256 >> 4, tx = t256 & 15;
    int i = bi * 16 + ty, j = bj * 16 + tx;
    const float* Ai = (i < RANK) ? (U + i) : (V + (i - RANK));
    const float* Aj = (j < RANK) ? (U + j) : (V + (j - RANK));
    int k0 = sub * 1024;
    float p0 = 0.f, p1 = 0.f, p2 = 0.f, p3 = 0.f;
#pragma unroll 4
    for (int k = k0; k < k0 + 1024; k += 4) {
      p0 += Ai[(size_t)k * RANK]       * Aj[(size_t)k * RANK];
      p1 += Ai[(size_t)(k + 1) * RANK] * Aj[(size_t)(k + 1) * RANK];
      p2 += Ai[(size_t)(k + 2) * RANK] * Aj[(size_t)(k + 2) * RANK];
      p3 += Ai[(size_t)(k + 3) * RANK] * Aj[(size_t)(k + 3) * RANK];
    }
    red[tid] = (p0 + p1) + (p2 + p3);
    __syncthreads();
    if (sub == 0) {
      float s = red[t256] + red[256 + t256];
      if (i < RANK) G[(i + RANK) * R2 + j] = -s;
      else          G[(i - RANK) * R2 + j] =  s;
    }
  } else {
    // Mrf chunk CI = (t_*4 + J)*64 + lg*16 + lr holds M[t_*16+lr][J*32+lg*8+e]
    int CI = (b - 128) * 512 + tid;         // 0..32767
    int lane = CI & 63, rest = CI >> 6;
    int lr = lane & 15, lg = lane >> 4;
    int J = rest & 3, t_ = rest >> 2;
    int i = t_ * 16 + lr, j0 = J * 32 + lg * 8;
    const float* src = (j0 < RANK) ? (U + (size_t)i * RANK + j0)
                                   : (V + (size_t)i * RANK + (j0 - RANK));
    float4 f0 = *(const float4*)src, f1 = *(const float4*)(src + 4);
    u16x8 h;
    h[0] = f2bf(f0.x); h[1] = f2bf(f0.y); h[2] = f2bf(f0.z); h[3] = f2bf(f0.w);
    h[4] = f2bf(f1.x); h[5] = f2bf(f1.y); h[6] = f2bf(f1.z); h[7] = f2bf(f1.w);
    *(u16x8*)(Mrf + (size_t)CI * 8) = h;
  }
}

// ---- 2) generic small 128x128 GEMM launch: O = (A + a*I)(B + b*I), fp32 ----
struct SOp { const float* A; const float* B; float* O; float a, b; };
struct SOps { SOp op[3]; };
__global__ void k_small(SOps ops) {
  SOp o = ops.op[blockIdx.x >> 6];     // 64 blocks per op
  smallGemm(o.A, o.B, o.O, o.a, o.b, blockIdx.x & 63, threadIdx.x);
}

// ---- 3) k_T1: T1bf = bf16(input @ M), 512 blocks of 32 rows + 64 G2-blocks.
// Wave w owns K-range [w*512,(w+1)*512). Input staged via per-wave swizzled LDS;
// M frags contiguous from Mf. Two-pass 16-row reduce epilogue keeps LDS at 36.9KB
// (4 blocks/CU vs 2 at the old [4][128][36] rbuf). Blocks >=512: G2 = G*G fold.
__global__ __launch_bounds__(256) void k_T1(const float* __restrict__ input,
                                            const unsigned short* __restrict__ Mf,
                                            unsigned short* __restrict__ T1bf,
                                            const float* __restrict__ G,
                                            float* __restrict__ G2) {
  __shared__ __align__(16) unsigned char lds[36864];  // abuf[w] 8KB x4 (32KB) / rbuf [4][18][128] f32 overlay
  if (blockIdx.x >= 512) {                  // s1 fold: G2 = G*G
    smallGemm(G, G, G2, 0.f, 0.f, blockIdx.x - 512, threadIdx.x);
    return;
  }
  const int tid = threadIdx.x, lane = tid & 63, w = tid >> 6;
  const int lr = lane & 15, lg = lane >> 4;
  const int row0 = blockIdx.x * 32;
  unsigned char* abuf = lds + w * 8192;

  f32x4 acc[2][8] = {};
  const float* gbase = input + (size_t)row0 * NIN + w * 512;
  const int Jbase = w * 16;
  float4 s0[8], s1[8];
  bf16x8 bx[8], by[8];

#define T1_SLOAD(KT)                                                          \
  _Pragma("unroll") for (int p = 0; p < 8; ++p) {                             \
    int id = p * 64 + lane; int r = id >> 4, C = id & 15;                     \
    const float* g = gbase + (size_t)r * NIN + (KT) * 128 + C * 8;            \
    s0[p] = *(const float4*)g; s1[p] = *(const float4*)(g + 4);               \
  }
#define T1_SWRITE()                                                           \
  _Pragma("unroll") for (int p = 0; p < 8; ++p) {                             \
    int id = p * 64 + lane; int r = id >> 4, C = id & 15;                     \
    u16x8 h;                                                                  \
    h[0] = f2bf(s0[p].x); h[1] = f2bf(s0[p].y);                               \
    h[2] = f2bf(s0[p].z); h[3] = f2bf(s0[p].w);                               \
    h[4] = f2bf(s1[p].x); h[5] = f2bf(s1[p].y);                               \
    h[6] = f2bf(s1[p].z); h[7] = f2bf(s1[p].w);                               \
    *(u16x8*)(abuf + r * 256 + ((C ^ (r & 7)) << 4)) = h;                     \
  }
#define T1_BLOAD(P, S)                                                        \
  _Pragma("unroll") for (int t = 0; t < 8; ++t)                               \
    P[t] = *(const bf16x8*)(Mf + ((size_t)(t * 64 + Jbase + (S)) * 64 + lane) * 8);

  T1_SLOAD(0);
  T1_SWRITE();
  T1_BLOAD(bx, 0);
#pragma unroll
  for (int s = 0; s < 16; ++s) {
    const int kt = s >> 2, j = s & 3;
    if (j == 0 && kt < 3) { T1_SLOAD(kt + 1); }
    bf16x8 a0, a1;
    {
      int C = j * 4 + lg;
      a0 = *(const bf16x8*)(abuf + lr * 256 + ((C ^ (lr & 7)) << 4));
      a1 = *(const bf16x8*)(abuf + (16 + lr) * 256 + ((C ^ ((16 + lr) & 7)) << 4));
    }
    if (s < 15) { if (s & 1) { T1_BLOAD(bx, s + 1); } else { T1_BLOAD(by, s + 1); } }
#pragma unroll
    for (int t = 0; t < 8; ++t) {
      bf16x8 bcur = (s & 1) ? by[t] : bx[t];
      acc[0][t] = __builtin_amdgcn_mfma_f32_16x16x32_bf16(a0, bcur, acc[0][t], 0, 0, 0);
      acc[1][t] = __builtin_amdgcn_mfma_f32_16x16x32_bf16(a1, bcur, acc[1][t], 0, 0, 0);
    }
    if (j == 3 && kt < 3) { T1_SWRITE(); }
  }

  // ---- two-pass reduce epilogue: rbuf [4][18 rows][128 cols] f32 (rows 16+2 pad) ----
  float* rbw = (float*)lds + (size_t)w * 2304;      // 18*128 floats per wave
#pragma unroll
  for (int m = 0; m < 2; ++m) {
    __syncthreads();                                // (m=0: abuf done) / (m=1: reduce reads done)
#pragma unroll
    for (int t = 0; t < 8; ++t) {
      int col = t * 16 + lr;
#pragma unroll
      for (int e = 0; e < 4; ++e) rbw[(lg * 4 + e) * 128 + col] = acc[m][t][e];
    }
    __syncthreads();
    {
      int r = tid >> 4, cg = tid & 15;              // row r (0..15), cols cg*8..+8
      f32x4 a0 = {}, a1 = {};
#pragma unroll
      for (int ww = 0; ww < 4; ++ww) {
        const float* p = (const float*)lds + (size_t)ww * 2304 + r * 128 + cg * 8;
        a0 += *(const f32x4*)p;
        a1 += *(const f32x4*)(p + 4);
      }
      u16x8 o;
#pragma unroll
      for (int i = 0; i < 4; ++i) { o[i] = f2bf(a0[i]); o[4 + i] = f2bf(a1[i]); }
      *(u16x8*)(T1bf + (size_t)(row0 + m * 16 + r) * R2 + cg * 8) = o;
    }
  }
}

// ---- 4) k_OUT: out = input + T2 @ M^T, with T2 = T1 @ C^T computed in-block.
// C[k][j] = sgn(j)*(2H - G15)[k][jj(j)]. 512 blocks x 256 thr; 32 rows x 2048 cols.
// Wave w owns cols [w*512,(w+1)*512). LDS 43008: cbuf 32KB (prologue) overlaid by
// obuf 4x[32][68] f32 (main); t2buf bf16 [32][128] swz at 34816. 3 blocks/CU.
__global__ __launch_bounds__(256) void k_OUT(const float* __restrict__ input,
                                             const unsigned short* __restrict__ T1bf,
                                             const float* __restrict__ Hm,
                                             const float* __restrict__ G15m,
                                             const unsigned short* __restrict__ Mrf,
                                             float* __restrict__ out) {
  __shared__ __align__(16) unsigned char lds[43008];
  unsigned char* cbuf = lds;
  unsigned char* t2buf = lds + 34816;
  const int tid = threadIdx.x, lane = tid & 63, w = tid >> 6;
  const int lr = lane & 15, lg = lane >> 4;
  const int row0 = blockIdx.x * 32;

  // ---- prologue A: cbuf[k][j-granule swz] = C row-major bf16 ----
#pragma unroll
  for (int it = 0; it < 8; ++it) {
    int id = it * 256 + tid;                 // chunk 0..2047
    int k = id >> 4, j8 = id & 15, j0 = j8 * 8;
    int jj0 = (j0 < RANK) ? j0 + RANK : j0 - RANK;
    float sgn = (j0 < RANK) ? -1.f : 1.f;
    const float* hp = Hm + k * R2 + jj0;
    const float* gp = G15m + k * R2 + jj0;
    float4 h0 = *(const float4*)hp, h1 = *(const float4*)(hp + 4);
    float4 g0 = *(const float4*)gp, g1 = *(const float4*)(gp + 4);
    u16x8 cv;
    cv[0] = f2bf(sgn * (2.f * h0.x - g0.x));
    cv[1] = f2bf(sgn * (2.f * h0.y - g0.y));
    cv[2] = f2bf(sgn * (2.f * h0.z - g0.z));
    cv[3] = f2bf(sgn * (2.f * h0.w - g0.w));
    cv[4] = f2bf(sgn * (2.f * h1.x - g1.x));
    cv[5] = f2bf(sgn * (2.f * h1.y - g1.y));
    cv[6] = f2bf(sgn * (2.f * h1.z - g1.z));
    cv[7] = f2bf(sgn * (2.f * h1.w - g1.w));
    *(u16x8*)(cbuf + k * 256 + ((j8 ^ (k & 7)) << 4)) = cv;
  }
  // T1 frags (B operand of T2-mfma): lane lr -> T1 row row0+R*16+lr
  bf16x8 t1f[2][4];
#pragma unroll
  for (int R = 0; R < 2; ++R)
#pragma unroll
    for (int J = 0; J < 4; ++J)
      t1f[R][J] = *(const bf16x8*)(T1bf + (size_t)(row0 + R * 16 + lr) * R2 + J * 32 + lg * 8);
  __syncthreads();                           // cbuf ready

  // ---- prologue B: T2[r][kc] = sum_j T1[r][j] C[kc][j]; wave w: kc-tiles {2w,2w+1} ----
#pragma unroll
  for (int kk = 0; kk < 2; ++kk) {
    int kct = w * 2 + kk;
    int kc = kct * 16 + lr;                  // C row this lane supplies
    f32x4 a2[2] = {};
#pragma unroll
    for (int jkt = 0; jkt < 4; ++jkt) {
      bf16x8 cf = *(const bf16x8*)(cbuf + kc * 256 + (((jkt * 4 + lg) ^ (kc & 7)) << 4));
#pragma unroll
      for (int R = 0; R < 2; ++R)
        a2[R] = __builtin_amdgcn_mfma_f32_16x16x32_bf16(cf, t1f[R][jkt], a2[R], 0, 0, 0);
    }
    // acc layout: col=lr -> r_local, row=lg*4+e -> kc = kct*16+lg*4+e
#pragma unroll
    for (int R = 0; R < 2; ++R) {
      int r = R * 16 + lr;
      ushort4 p;
      p.x = f2bf(a2[R][0]); p.y = f2bf(a2[R][1]);
      p.z = f2bf(a2[R][2]); p.w = f2bf(a2[R][3]);
      int gran = kct * 2 + (lg >> 1), off = (lg & 1) * 8;
      *(ushort4*)(t2buf + r * 256 + ((gran ^ (r & 7)) << 4) + off) = p;
    }
  }
  __syncthreads();                           // t2buf ready; cbuf dead (obuf may overlay)

  // bq = T2 frags: lane lr -> row R*16+lr, k-slice J*32+lg*8
  bf16x8 bq[2][4];
#pragma unroll
  for (int R = 0; R < 2; ++R)
#pragma unroll
    for (int J = 0; J < 4; ++J) {
      int row = R * 16 + lr;
      bq[R][J] = *(const bf16x8*)(t2buf + row * 256 + (((J * 4 + lg) ^ (row & 7)) << 4));
    }

  // ---- main loop: verified round-7 epilogue shape (64-col groups, [32][68] obuf) ----
  float* obufw = (float*)(lds + w * 8704);   // per-wave [32][68] f32
  bf16x8 xd[4], yd[4];
#define O_DLOAD(P, TTI)                                                       \
  _Pragma("unroll") for (int J = 0; J < 4; ++J)                               \
    P[J] = *(const bf16x8*)(Mrf + ((size_t)((w * 32 + (TTI)) * 4 + J) * 64 + lane) * 8);

  O_DLOAD(xd, 0);
#pragma unroll
  for (int g = 0; g < 8; ++g) {
#pragma unroll
    for (int tt = 0; tt < 4; ++tt) {
      const int tti = g * 4 + tt;
      if (tti < 31) { if (tti & 1) { O_DLOAD(xd, tti + 1); } else { O_DLOAD(yd, tti + 1); } }
#pragma unroll
      for (int R = 0; R < 2; ++R) {
        f32x4 o = {};
#pragma unroll
        for (int J = 0; J < 4; ++J) {
          bf16x8 d = (tti & 1) ? yd[J] : xd[J];
          o = __builtin_amdgcn_mfma_f32_16x16x32_bf16(d, bq[R][J], o, 0, 0, 0);
        }
        *(f32x4*)&obufw[(R * 16 + lr) * 68 + tt * 16 + lg * 4] = o;
      }
    }
#pragma unroll
    for (int c = 0; c < 8; ++c) {
      int id = c * 64 + lane, r = id >> 4, cc = id & 15;
      f32x4 v = *(const f32x4*)&obufw[r * 68 + cc * 4];
      int grow = row0 + r, gcol = w * 512 + g * 64 + cc * 4;
      float4 inv = *(const float4*)(input + (size_t)grow * NIN + gcol);
      float4 res = { v[0] + inv.x, v[1] + inv.y, v[2] + inv.z, v[3] + inv.w };
      *(float4*)(out + (size_t)grow * NIN + gcol) = res;
    }
  }
}

extern "C" void kernel_launch(void* const* d_in, const int* in_sizes, int n_in,
                              void* d_out, int out_size, void* d_ws, size_t ws_size,
                              hipStream_t stream) {
  const float* input = (const float*)d_in[0];
  const float* U     = (const float*)d_in[1];
  const float* V     = (const float*)d_in[2];
  float* out = (float*)d_out;
  char* ws = (char*)d_ws;

  // workspace layout
  float* mats = (float*)ws;                       // 10 x 128x128 fp32 = 640 KB
  float* G   = mats + 0 * 16384;
  float* G2  = mats + 1 * 16384;
  float* G3  = mats + 2 * 16384;
  float* G4  = mats + 3 * 16384;
  float* G7  = mats + 4 * 16384;
  float* G8  = mats + 5 * 16384;
  float* H12 = mats + 6 * 16384;
  float* H124= mats + 7 * 16384;
  float* H   = mats + 8 * 16384;
  float* G15 = mats + 9 * 16384;
  unsigned short* Mf   = (unsigned short*)(ws + 10 * 65536);              // 512 KB frag-order M (K=2048)
  unsigned short* Mrf  = (unsigned short*)(ws + 10 * 65536 + 524288);     // 512 KB frag-order M rows (K=128)
  unsigned short* T1bf = (unsigned short*)(ws + 10 * 65536 + 2 * 524288); // 4 MB

  k_prep<<<192, 512, 0, stream>>>(U, V, Mf, Mrf, G);
  k_T1<<<576, 256, 0, stream>>>(input, Mf, T1bf, G, G2);   // + s1 fold (G2)

  { SOps o = {{ {G2, G2, G4, 0.f, 0.f}, {G2, G, G3, 0.f, 0.f}, {G, G2, H12, 1.f, 1.f} }};
    k_small<<<192, 256, 0, stream>>>(o); }
  { SOps o = {{ {G4, G4, G8, 0.f, 0.f}, {G3, G4, G7, 0.f, 0.f}, {H12, G4, H124, 0.f, 1.f} }};
    k_small<<<192, 256, 0, stream>>>(o); }
  { SOps o = {{ {G7, G8, G15, 0.f, 0.f}, {H124, G8, H, 0.f, 1.f}, {nullptr,nullptr,nullptr,0.f,0.f} }};
    k_small<<<128, 256, 0, stream>>>(o); }

  k_OUT<<<512, 256, 0, stream>>>(input, T1bf, H, G15, Mrf, out);
}